// Round 13
// baseline (2290.009 us; speedup 1.0000x reference)
//
#include <hip/hip_runtime.h>
#include <math.h>

#define ICC  196
#define BLK  256
#define WSTR 28     // dwords per packed cell: W1[12] b1[6] W2[6] b2[1] pad[3]

#define SFENCE __builtin_amdgcn_sched_barrier(0)

// ---- prep: pack per-cell weights contiguously into d_ws ([195][28] f32) ----
__global__ void pack_w(const float* __restrict__ W1, const float* __restrict__ b1,
                       const float* __restrict__ W2, const float* __restrict__ b2,
                       float* __restrict__ ws)
{
    const int c = threadIdx.x;           // single block of 256
    if (c < 195) {
        float* o = ws + c * WSTR;
        #pragma unroll
        for (int k = 0; k < 12; ++k) o[k] = W1[c * 12 + k];
        #pragma unroll
        for (int k = 0; k < 6; ++k)  o[12 + k] = b1[c * 6 + k];
        #pragma unroll
        for (int k = 0; k < 6; ++k)  o[18 + k] = W2[c * 6 + k];
        o[24] = b2[c]; o[25] = 0.f; o[26] = 0.f; o[27] = 0.f;
    }
}

// One ReLU cell, weights via VGPR-addressed global loads (wave-uniform addr ->
// single L1 access broadcast; in-order counted vmcnt; all-VGPR fma operands).
// Layout (same mapping R11 verified on-device): q0={w1x0..3} q1={w1x4,w1x5,
// w1y0,w1y1} q2={w1y2..5} q3={b1_0..3} q4={b1_4,b1_5,w2_0,w2_1} q5={w2_2..5}.
__device__ __forceinline__ float cellV(float xi, float y, const float* wb)
{
    float4 q0 = *reinterpret_cast<const float4*>(wb + 0);
    float4 q1 = *reinterpret_cast<const float4*>(wb + 4);
    float4 q2 = *reinterpret_cast<const float4*>(wb + 8);
    float4 q3 = *reinterpret_cast<const float4*>(wb + 12);
    float4 q4 = *reinterpret_cast<const float4*>(wb + 16);
    float4 q5 = *reinterpret_cast<const float4*>(wb + 20);
    float  e  = wb[24];
    float h0 = fmaxf(fmaf(y, q1.z, fmaf(xi, q0.x, q3.x)), 0.f);
    float h1 = fmaxf(fmaf(y, q1.w, fmaf(xi, q0.y, q3.y)), 0.f);
    float h2 = fmaxf(fmaf(y, q2.x, fmaf(xi, q0.z, q3.z)), 0.f);
    float h3 = fmaxf(fmaf(y, q2.y, fmaf(xi, q0.w, q3.w)), 0.f);
    float h4 = fmaxf(fmaf(y, q2.z, fmaf(xi, q1.x, q4.x)), 0.f);
    float h5 = fmaxf(fmaf(y, q2.w, fmaf(xi, q1.y, q4.y)), 0.f);
    float s0 = fmaf(h0, q4.z, fmaf(h1, q4.w, e));
    float s1 = fmaf(h2, q5.x, h3 * q5.y);
    float s2 = fmaf(h4, q5.z, h5 * q5.w);
    return fmaxf(s0 + (s1 + s2), 0.f);
}

// 16 cells; WQ is the iteration-local packed-weight pointer (VGPR-offset),
// JB compile-time -> all weight loads use immediate offsets (< 4096 B).
#define CV(XI, J) y = cellV((XI), y, wq + (J) * WSTR);
#define B16V(JB, X0, X1, X2, X3)                      \
  {                                                   \
    CV(X0.x, (JB)+0)  CV(X0.y, (JB)+1)                \
    CV(X0.z, (JB)+2)  CV(X0.w, (JB)+3)                \
    CV(X1.x, (JB)+4)  CV(X1.y, (JB)+5)                \
    CV(X1.z, (JB)+6)  CV(X1.w, (JB)+7)                \
    CV(X2.x, (JB)+8)  CV(X2.y, (JB)+9)                \
    CV(X2.z, (JB)+10) CV(X2.w, (JB)+11)               \
    CV(X3.x, (JB)+12) CV(X3.y, (JB)+13)               \
    CV(X3.z, (JB)+14) CV(X3.w, (JB)+15)               \
  }

__global__ __launch_bounds__(BLK, 4) void rnn_kernel(
    const float* __restrict__ x,    // [P, 196]
    const float* __restrict__ wsf,  // [195, 28] packed weights (d_ws)
    const float* __restrict__ Wf1,  // [2, 6]
    const float* __restrict__ bf1,  // [6]
    const float* __restrict__ Wf2,  // [6]
    const float* __restrict__ bf2,  // [1]
    float* __restrict__ out,        // [P]
    int npoints)
{
    const int tid = threadIdx.x;
    const int p   = blockIdx.x * BLK + tid;
    const int pc  = (p < npoints) ? p : (npoints - 1);
    const float4* __restrict__ r4 =
        reinterpret_cast<const float4*>(x + (size_t)pc * ICC);

    // opaque per-lane zero: forces the weight pointer into a VGPR so the
    // compiler emits global_load (counted vmcnt), NOT s_load (OOO lgkmcnt).
    int zoff;
    asm volatile("v_mov_b32 %0, 0" : "=v"(zoff));
    const float* wq = wsf + zoff;    // advanced by 32*WSTR per loop iteration

    // double-buffered 64B x-chunk sets (named regs, NO arrays) + tail
    float4 A0,A1,A2,A3, B0,B1,B2,B3, T;
    A0 = r4[0]; A1 = r4[1]; A2 = r4[2]; A3 = r4[3];   // ch 0..15
    B0 = r4[4]; B1 = r4[5]; B2 = r4[6]; B3 = r4[7];   // ch 16..31
    T  = r4[48];                                      // ch 192..195
    SFENCE;

    float y = A0.x;   // y0 = channel 0

    // 12 chunks of 16 cells; reload just-consumed x-set with chunk c+2.
    // No LDS, no barriers, no SMEM in the loop: every wait is a counted
    // per-wave vmcnt the compiler schedules; 4 waves/SIMD cover the rest.
    #pragma unroll 1
    for (int c2 = 0; c2 < 12; c2 += 2) {
        B16V(0, A0, A1, A2, A3);
        if (c2 < 10) {
            const float4* q = r4 + (c2 + 2) * 4;
            A0 = q[0]; A1 = q[1]; A2 = q[2]; A3 = q[3];
            SFENCE;
        }
        B16V(16, B0, B1, B2, B3);
        if (c2 < 10) {
            const float4* q = r4 + (c2 + 3) * 4;
            B0 = q[0]; B1 = q[1]; B2 = q[2]; B3 = q[3];
            SFENCE;
        }
        wq += 32 * WSTR;
    }

    // tail: cells 192..194 (packed weights), then the final sigmoid cell
    y = cellV(T.x, y, wq + 0 * WSTR);    // cell 192 (wq now at cell 192)
    y = cellV(T.y, y, wq + 1 * WSTR);    // cell 193
    y = cellV(T.z, y, wq + 2 * WSTR);    // cell 194

    const float xf = T.w;
    float h0 = fmaxf(fmaf(y, Wf1[6],  fmaf(xf, Wf1[0], bf1[0])), 0.0f);
    float h1 = fmaxf(fmaf(y, Wf1[7],  fmaf(xf, Wf1[1], bf1[1])), 0.0f);
    float h2 = fmaxf(fmaf(y, Wf1[8],  fmaf(xf, Wf1[2], bf1[2])), 0.0f);
    float h3 = fmaxf(fmaf(y, Wf1[9],  fmaf(xf, Wf1[3], bf1[3])), 0.0f);
    float h4 = fmaxf(fmaf(y, Wf1[10], fmaf(xf, Wf1[4], bf1[4])), 0.0f);
    float h5 = fmaxf(fmaf(y, Wf1[11], fmaf(xf, Wf1[5], bf1[5])), 0.0f);
    float s0 = fmaf(h0, Wf2[0], fmaf(h1, Wf2[1], bf2[0]));
    float s1 = fmaf(h2, Wf2[2], h3 * Wf2[3]);
    float s2 = fmaf(h4, Wf2[4], h5 * Wf2[5]);
    float t  = s0 + (s1 + s2);

    if (p < npoints)
        out[p] = 1.0f / (1.0f + __expf(-t));
}

extern "C" void kernel_launch(void* const* d_in, const int* in_sizes, int n_in,
                              void* d_out, int out_size, void* d_ws, size_t ws_size,
                              hipStream_t stream) {
    const float* x   = (const float*)d_in[0];
    const float* W1  = (const float*)d_in[1];
    const float* b1  = (const float*)d_in[2];
    const float* W2  = (const float*)d_in[3];
    const float* b2  = (const float*)d_in[4];
    const float* Wf1 = (const float*)d_in[5];
    const float* bf1 = (const float*)d_in[6];
    const float* Wf2 = (const float*)d_in[7];
    const float* bf2 = (const float*)d_in[8];
    float* out = (float*)d_out;
    float* wsf = (float*)d_ws;                    // needs 195*28*4 = 21840 B

    pack_w<<<1, 256, 0, stream>>>(W1, b1, W2, b2, wsf);

    const int npoints = out_size;                 // B*N = 262144
    const int grid = (npoints + BLK - 1) / BLK;   // 1024 blocks -> 4/CU
    rnn_kernel<<<grid, BLK, 0, stream>>>(x, wsf, Wf1, bf1, Wf2, bf2,
                                         out, npoints);
}